// Round 8
// baseline (180.570 us; speedup 1.0000x reference)
//
#include <hip/hip_runtime.h>
#include <stdint.h>

#define NB    1024   // batch
#define NUM   512    // nodes
#define HD    64     // hidden dim
#define NE    4096   // edges
#define NEP   4608   // padded edge capacity
#define MAIN  10     // softmax segment

typedef _Float16 hlf;
typedef __attribute__((ext_vector_type(2))) _Float16 hlf2;
typedef __attribute__((ext_vector_type(8))) _Float16 hlf8;
typedef __attribute__((ext_vector_type(4))) float f32x4;

__device__ __forceinline__ unsigned short f2h(float f) {
    hlf v = (hlf)f;
    return __builtin_bit_cast(unsigned short, v);
}

// ---------------------------------------------------------------------------
// Prep: block 0 builds degree-sorted CSR (for SpMM3) + scatters dense S32;
// blocks 1..72 build E1T = (emb@W1)^T and W2T = W2^T in f16.
// ---------------------------------------------------------------------------
__global__ __launch_bounds__(512) void prep_all(
    const int* __restrict__ erow, const int* __restrict__ ecol,
    const float* __restrict__ emb, const float* __restrict__ W1,
    const float* __restrict__ W2,
    int* __restrict__ rsptr, int* __restrict__ colmap, int* __restrict__ epk,
    short* __restrict__ E1T, short* __restrict__ W2T,
    float* __restrict__ S32)
{
    const int t = threadIdx.x;
    if (blockIdx.x != 0) {
        int g = (blockIdx.x - 1) * 512 + t;     // 72 x 512 = 36864
        if (g < NUM * HD) {
            int dim = g >> 9, node = g & 511;   // E1T layout [dim][node]
            float acc = 0.0f;
            #pragma unroll
            for (int k = 0; k < HD; ++k) acc += emb[node * HD + k] * W1[k * HD + dim];
            E1T[g] = (short)f2h(acc);
        } else if (g < NUM * HD + HD * HD) {
            int j = g - NUM * HD;
            int dout = j >> 6, din = j & 63;
            W2T[j] = (short)f2h(W2[din * HD + dout]);
        }
        return;
    }

    __shared__ int   sdeg[NUM];
    __shared__ int   aux[NUM];
    __shared__ float sdv[NUM];
    __shared__ int   rnk[NUM];
    __shared__ int   rdg[NUM];
    __shared__ int   wsum[8];

    const int lane = t & 63, wv = t >> 6;

    sdeg[t] = 0; aux[t] = 0;
    __syncthreads();
    for (int e = t; e < NE; e += 512) atomicAdd(&sdeg[ecol[e]], 1);
    __syncthreads();
    const int deg  = sdeg[t];
    const int pdeg = (deg + 1) & ~1;
    const int dbin = deg < NUM ? deg : NUM - 1;
    sdv[t] = deg > 0 ? rsqrtf((float)deg) : 0.0f;
    atomicAdd(&aux[dbin], 1);
    __syncthreads();
    {
        int v = aux[t];
        #pragma unroll
        for (int ofs = 1; ofs < 64; ofs <<= 1) {
            int sh = __shfl_up(v, ofs, 64);
            if (lane >= ofs) v += sh;
        }
        if (lane == 63) wsum[wv] = v;
        __syncthreads();
        if (t == 0) {
            int s = 0;
            #pragma unroll
            for (int w = 0; w < 8; ++w) { int tmp = wsum[w]; wsum[w] = s; s += tmp; }
        }
        __syncthreads();
        int inc = v + wsum[wv];
        aux[t]  = inc;
        __syncthreads();
        sdeg[t] = (t == 0) ? 0 : aux[t - 1];
        __syncthreads();
    }
    {
        int r = atomicAdd(&sdeg[dbin], 1);
        rnk[t] = r;
        rdg[r] = pdeg;
        colmap[r] = t;
    }
    __syncthreads();
    {
        int dv = rdg[t], v = dv;
        #pragma unroll
        for (int ofs = 1; ofs < 64; ofs <<= 1) {
            int sh = __shfl_up(v, ofs, 64);
            if (lane >= ofs) v += sh;
        }
        if (lane == 63) wsum[wv] = v;
        __syncthreads();
        if (t == 0) {
            int s = 0;
            #pragma unroll
            for (int w = 0; w < 8; ++w) { int tmp = wsum[w]; wsum[w] = s; s += tmp; }
        }
        __syncthreads();
        int inc  = v + wsum[wv];
        int excl = inc - dv;
        rsptr[t] = excl;
        if (t == NUM - 1) rsptr[NUM] = inc;
        aux[t] = excl;
        __syncthreads();
    }
    sdeg[t] = aux[rnk[t]];
    __syncthreads();
    for (int i = t; i < NEP; i += 512) epk[i] = 0;
    __syncthreads();
    for (int e = t; e < NE; e += 512) {
        int c = ecol[e], rr = erow[e];
        int p = atomicAdd(&sdeg[c], 1);
        float nf = sdv[rr] * sdv[c];
        unsigned ns = (unsigned)f2h(nf);
        epk[p] = (rr << 16) | (int)ns;          // hi16 = row index
        atomicAdd(&S32[c * NUM + rr], nf);      // dense S (dup edges accumulate)
    }
}

// ---------------------------------------------------------------------------
// Cast S32 -> Sfr: f16 in MFMA A-fragment order. Fragment f = mt*16+kt holds
// the 16x32 tile A[mt*16 .. +16][kt*32 .. +32]; lane l owns row (l&15),
// k-chunk (l>>4)*8 — stored at Sfr + f*1024B + l*16B (wave load = 1KB coalesced)
// ---------------------------------------------------------------------------
__global__ __launch_bounds__(1024) void cast_S(
    const float* __restrict__ S32, hlf* __restrict__ Sfr)
{
    int idx = blockIdx.x * 1024 + threadIdx.x;  // 0..32767 = 512 frags x 64 lanes
    int f = idx >> 6, l = idx & 63;
    int mt = f >> 4, kt = f & 15;
    int c  = mt * 16 + (l & 15);
    int r0 = kt * 32 + (l >> 4) * 8;
    const float* src = S32 + c * NUM + r0;
    hlf8 o;
    #pragma unroll
    for (int j = 0; j < 8; ++j) o[j] = (hlf)src[j];
    *(hlf8*)(Sfr + idx * 8) = o;
}

// ---------------------------------------------------------------------------
// Body: one block (1024 thr, 16 waves) per batch element. All aggregations on
// matrix cores with dense S (A-operand, streamed from L2 in fragment order):
//   H0^T = (x .* E1)^T in LDS (XOR-swizzled [dim][node])
//   layer1: agg1 = S@H0 (MFMA) ; h1^T = relu(agg1+b1)^T -> AG (swizzled)
//   layer2: agg2 = S@h1 (MFMA) -> HT row-major swizzled [node][dim]
//   z2 = agg2@W2 + b2 (MFMA); tv[node] = sum_d relu(z2).W3
//   SpMM3 (scalar, tiny): logits = S@tv + b3; softmax/sigmoid
// ---------------------------------------------------------------------------
__global__ __launch_bounds__(1024, 4) void gcn_body(
    const float* __restrict__ x, const hlf* __restrict__ E1T,
    const hlf* __restrict__ W2T, const hlf* __restrict__ Sfr,
    const float* __restrict__ b1, const float* __restrict__ b2,
    const float* __restrict__ W3, const float* __restrict__ b3,
    const int* __restrict__ rsptrg, const int* __restrict__ cmapg,
    const int* __restrict__ epkg,
    float* __restrict__ out)
{
    __shared__ hlf   HT[HD * NUM];   // 64KB: H0^T (swz), then agg2 (row-major swz)
    __shared__ hlf   AG[HD * NUM];   // 64KB: h1^T (swz)
    __shared__ float xs[NUM];
    __shared__ float tv[NUM];
    __shared__ float slog[NUM];
    __shared__ float sred[2];

    const int t    = threadIdx.x;
    const int b    = blockIdx.x;
    const int lane = t & 63;
    const int wave = t >> 6;           // 0..15
    const int q    = lane >> 4;        // 0..3
    const int l15  = lane & 15;

    if (t < NUM) xs[t] = x[b * NUM + t];
    __syncthreads();

    // ---- build H0^T[d][r] = x[r]*E1[r][d], swizzled
    #pragma unroll
    for (int p = 0; p < 4; ++p) {
        int i = t + p * 1024;          // 4096 chunks of 8
        int d = i >> 6, r0 = (i & 63) * 8;
        hlf8 ev = *(const hlf8*)&E1T[d * NUM + r0];
        hlf8 o;
        #pragma unroll
        for (int j = 0; j < 8; ++j) o[j] = ev[j] * (hlf)xs[r0 + j];
        *(hlf8*)((char*)HT + d * 1024 + ((r0 * 2) ^ ((d & 7) << 4))) = o;
    }

    // per-lane scalars
    float b1l[4], b2l[4], w3l[4];
    #pragma unroll
    for (int nt = 0; nt < 4; ++nt) {
        b1l[nt] = b1[nt * 16 + l15];
        b2l[nt] = b2[nt * 16 + l15];
        w3l[nt] = W3[nt * 16 + l15];
    }
    __syncthreads();

    // ---- layer1: agg1 = S@H0 ; AG = relu(agg1+b1)^T (swizzled)
    {
        f32x4 acc[2][4];
        #pragma unroll
        for (int mm = 0; mm < 2; ++mm)
            #pragma unroll
            for (int nt = 0; nt < 4; ++nt) acc[mm][nt] = (f32x4){0.f, 0.f, 0.f, 0.f};
        #pragma unroll
        for (int kt = 0; kt < 16; ++kt) {
            hlf8 bf[4];
            #pragma unroll
            for (int nt = 0; nt < 4; ++nt) {
                int row = nt * 16 + l15;
                bf[nt] = *(const hlf8*)((const char*)HT + row * 1024 +
                             ((kt * 64 + q * 16) ^ ((row & 7) << 4)));
            }
            #pragma unroll
            for (int mm = 0; mm < 2; ++mm) {
                hlf8 af = *(const hlf8*)((const char*)Sfr +
                              (((wave * 2 + mm) * 16 + kt) << 10) + lane * 16);
                #pragma unroll
                for (int nt = 0; nt < 4; ++nt)
                    acc[mm][nt] = __builtin_amdgcn_mfma_f32_16x16x32_f16(
                        af, bf[nt], acc[mm][nt], 0, 0, 0);
            }
        }
        #pragma unroll
        for (int mm = 0; mm < 2; ++mm) {
            int mt = wave * 2 + mm;
            #pragma unroll
            for (int nt = 0; nt < 4; ++nt) {
                int n = nt * 16 + l15;
                uint2 pk;
                pk.x = __builtin_bit_cast(unsigned, __builtin_amdgcn_cvt_pkrtz(
                           fmaxf(acc[mm][nt][0] + b1l[nt], 0.0f),
                           fmaxf(acc[mm][nt][1] + b1l[nt], 0.0f)));
                pk.y = __builtin_bit_cast(unsigned, __builtin_amdgcn_cvt_pkrtz(
                           fmaxf(acc[mm][nt][2] + b1l[nt], 0.0f),
                           fmaxf(acc[mm][nt][3] + b1l[nt], 0.0f)));
                *(uint2*)((char*)AG + n * 1024 +
                          ((mt * 32 + q * 8) ^ ((n & 7) << 4))) = pk;
            }
        }
    }
    __syncthreads();

    // ---- layer2: agg2 = S@h1 -> HT row-major swizzled [node][dim]
    {
        f32x4 acc[2][4];
        #pragma unroll
        for (int mm = 0; mm < 2; ++mm)
            #pragma unroll
            for (int nt = 0; nt < 4; ++nt) acc[mm][nt] = (f32x4){0.f, 0.f, 0.f, 0.f};
        #pragma unroll
        for (int kt = 0; kt < 16; ++kt) {
            hlf8 bf[4];
            #pragma unroll
            for (int nt = 0; nt < 4; ++nt) {
                int row = nt * 16 + l15;
                bf[nt] = *(const hlf8*)((const char*)AG + row * 1024 +
                             ((kt * 64 + q * 16) ^ ((row & 7) << 4)));
            }
            #pragma unroll
            for (int mm = 0; mm < 2; ++mm) {
                hlf8 af = *(const hlf8*)((const char*)Sfr +
                              (((wave * 2 + mm) * 16 + kt) << 10) + lane * 16);
                #pragma unroll
                for (int nt = 0; nt < 4; ++nt)
                    acc[mm][nt] = __builtin_amdgcn_mfma_f32_16x16x32_f16(
                        af, bf[nt], acc[mm][nt], 0, 0, 0);
            }
        }
        __syncthreads();   // all AG reads done; HT reusable as agg2
        #pragma unroll
        for (int mm = 0; mm < 2; ++mm) {
            #pragma unroll
            for (int nt = 0; nt < 4; ++nt) {
                int n = nt * 16 + l15;
                #pragma unroll
                for (int i = 0; i < 4; ++i) {
                    int m = (wave * 2 + mm) * 16 + q * 4 + i;
                    *(hlf*)((char*)HT + m * 128 + ((n * 2) ^ ((m & 7) << 4))) =
                        (hlf)acc[mm][nt][i];
                }
            }
        }
    }
    __syncthreads();

    // ---- z2 = agg2@W2 + b2; tv[node] = sum_n relu(z2).W3
    {
        hlf8 wb[2][4];
        #pragma unroll
        for (int kt = 0; kt < 2; ++kt)
            #pragma unroll
            for (int nt = 0; nt < 4; ++nt)
                wb[kt][nt] = *(const hlf8*)&W2T[(nt * 16 + l15) * HD + kt * 32 + q * 8];
        #pragma unroll
        for (int mm = 0; mm < 2; ++mm) {
            int mt = wave * 2 + mm;
            f32x4 z[4];
            #pragma unroll
            for (int nt = 0; nt < 4; ++nt) z[nt] = (f32x4){0.f, 0.f, 0.f, 0.f};
            #pragma unroll
            for (int kt = 0; kt < 2; ++kt) {
                int m = mt * 16 + l15;
                hlf8 af = *(const hlf8*)((const char*)HT + m * 128 +
                              ((kt * 64 + q * 16) ^ ((m & 7) << 4)));
                #pragma unroll
                for (int nt = 0; nt < 4; ++nt)
                    z[nt] = __builtin_amdgcn_mfma_f32_16x16x32_f16(
                        af, wb[kt][nt], z[nt], 0, 0, 0);
            }
            float vs[4] = {0.f, 0.f, 0.f, 0.f};
            #pragma unroll
            for (int nt = 0; nt < 4; ++nt)
                #pragma unroll
                for (int i = 0; i < 4; ++i)
                    vs[i] += fmaxf(z[nt][i] + b2l[nt], 0.0f) * w3l[nt];
            #pragma unroll
            for (int i = 0; i < 4; ++i) {
                float v = vs[i];
                v += __shfl_xor(v, 1, 64);
                v += __shfl_xor(v, 2, 64);
                v += __shfl_xor(v, 4, 64);
                v += __shfl_xor(v, 8, 64);
                if (l15 == 0) tv[mt * 16 + q * 4 + i] = v;
            }
        }
    }
    __syncthreads();

    // ---- SpMM3: slog[col] = (S @ tv)[col] + b3   (2 threads per rank)
    {
        int rk = t >> 1, hh = t & 1;
        int e0 = rsptrg[rk], e1 = rsptrg[rk + 1];
        int mid = (e0 + e1) >> 1;
        int ea = hh ? mid : e0;
        int eb = hh ? e1 : mid;
        float acc = 0.0f;
        for (int e = ea; e < eb; ++e) {
            unsigned pe = (unsigned)epkg[e];
            float nf = (float)__builtin_bit_cast(hlf2, pe)[0];
            acc = fmaf(nf, tv[pe >> 16], acc);
        }
        acc += __shfl_xor(acc, 1, 64);
        if (!hh) slog[cmapg[rk]] = acc + b3[0];
    }
    __syncthreads();

    // ---- softmax stats over [0, MAIN)
    if (t < 64) {
        float v = (t < MAIN) ? slog[t] : -1e30f;
        float m = v;
        m = fmaxf(m, __shfl_xor(m, 1, 64));
        m = fmaxf(m, __shfl_xor(m, 2, 64));
        m = fmaxf(m, __shfl_xor(m, 4, 64));
        m = fmaxf(m, __shfl_xor(m, 8, 64));
        float ev = (t < MAIN) ? __expf(v - m) : 0.0f;
        ev += __shfl_xor(ev, 1, 64);
        ev += __shfl_xor(ev, 2, 64);
        ev += __shfl_xor(ev, 4, 64);
        ev += __shfl_xor(ev, 8, 64);
        if (t == 0) { sred[0] = m; sred[1] = ev; }
    }
    __syncthreads();

    if (t < NUM) {
        float l = slog[t];
        float o = (t < MAIN) ? __expf(l - sred[0]) / sred[1]
                             : 1.0f / (1.0f + __expf(-l));
        out[b * NUM + t] = o;
    }
}

// ---------------------------------------------------------------------------
extern "C" void kernel_launch(void* const* d_in, const int* in_sizes, int n_in,
                              void* d_out, int out_size, void* d_ws, size_t ws_size,
                              hipStream_t stream) {
    const float* x    = (const float*)d_in[0];
    const float* emb  = (const float*)d_in[1];
    const float* W1   = (const float*)d_in[2];
    const float* b1   = (const float*)d_in[3];
    const float* W2   = (const float*)d_in[4];
    const float* b2   = (const float*)d_in[5];
    const float* W3   = (const float*)d_in[6];
    const float* b3   = (const float*)d_in[7];
    const int*   erow = (const int*)d_in[8];
    const int*   ecol = (const int*)d_in[9];

    char* ws = (char*)d_ws;
    float* S32   = (float*)ws;               // 1 MB   [0, 1048576)
    short* Sfr   = (short*)(ws + 1048576);   // 512 KB [1048576, 1572864)
    short* E1T   = (short*)(ws + 1572864);   // 64 KB  [1572864, 1638400)
    short* W2T   = (short*)(ws + 1638400);   // 8 KB   [1638400, 1646592)
    int*   epk   = (int*)(ws + 1646592);     // 18 KB  [1646592, 1665024)
    int*   rsptr = (int*)(ws + 1665024);     // 2052 B
    int*   colmap= (int*)(ws + 1667200);     // 2048 B

    hipMemsetAsync(S32, 0, NUM * NUM * sizeof(float), stream);
    prep_all<<<73, 512, 0, stream>>>(erow, ecol, emb, W1, W2,
                                     rsptr, colmap, epk, E1T, W2T, S32);
    cast_S<<<32, 1024, 0, stream>>>(S32, (hlf*)Sfr);
    gcn_body<<<NB, 1024, 0, stream>>>(x, (const hlf*)E1T, (const hlf*)W2T,
                                      (const hlf*)Sfr, b1, b2, W3, b3,
                                      rsptr, colmap, epk, (float*)d_out);
}